// Round 2
// baseline (3297.468 us; speedup 1.0000x reference)
//
#include <hip/hip_runtime.h>
#include <hip/hip_bf16.h>

#define NSPEC 4
#define NFEAT 144
#define RCUT 5.0f

// feature block offsets for l = 0..3 (n_max = 12,10,8,6; each block n_max*4 wide)
__device__ __constant__ int kNmax[4] = {12, 10, 8, 6};
__device__ __constant__ int kOff[4]  = {0, 48, 88, 120};

// ---------- explicit output zeroing (graph-capture-safe, unlike hipMemsetAsync) ----------

__global__ void zero_kernel(float* __restrict__ out, int n) {
    int n4 = n >> 2;
    float4* o4 = (float4*)out;
    for (int i = blockIdx.x * blockDim.x + threadIdx.x; i < n4; i += gridDim.x * blockDim.x) {
        o4[i] = make_float4(0.f, 0.f, 0.f, 0.f);
    }
    // tail (n is 144*NC, divisible by 4, but keep it safe)
    int tail = n & 3;
    if (blockIdx.x == 0 && threadIdx.x < tail) out[n4 * 4 + threadIdx.x] = 0.f;
}

// ---------- stable counting-sort rank of centers by species ----------

__global__ void count_kernel(const int* __restrict__ cs, int n, int* __restrict__ chunkCounts) {
    __shared__ int cnt[NSPEC];
    if (threadIdx.x < NSPEC) cnt[threadIdx.x] = 0;
    __syncthreads();
    int i = blockIdx.x * blockDim.x + threadIdx.x;
    if (i < n) atomicAdd(&cnt[cs[i]], 1);
    __syncthreads();
    if (threadIdx.x < NSPEC) chunkCounts[blockIdx.x * NSPEC + threadIdx.x] = cnt[threadIdx.x];
}

__global__ void scan_kernel(const int* __restrict__ chunkCounts, int nChunks,
                            int* __restrict__ chunkOffsets, int* __restrict__ speciesBase) {
    // phase 1: per-species exclusive scan over chunks (threads 0..3)
    if (threadIdx.x < NSPEC) {
        int s = threadIdx.x;
        int run = 0;
        for (int c = 0; c < nChunks; ++c) {
            chunkOffsets[c * NSPEC + s] = run;
            run += chunkCounts[c * NSPEC + s];
        }
        speciesBase[s] = run;  // total for species s, for now
    }
    __syncthreads();
    // phase 2: exclusive prefix over species totals -> bases
    if (threadIdx.x == 0) {
        int base = 0;
        for (int s = 0; s < NSPEC; ++s) {
            int t = speciesBase[s];
            speciesBase[s] = base;
            base += t;
        }
    }
    __syncthreads();
    // phase 3: fold species base into chunk offsets
    for (int i = threadIdx.x; i < nChunks * NSPEC; i += blockDim.x) {
        chunkOffsets[i] += speciesBase[i & (NSPEC - 1)];
    }
}

__global__ void dest_kernel(const int* __restrict__ cs, int n,
                            const int* __restrict__ chunkOffsets, int* __restrict__ dest) {
    __shared__ int waveCnt[4][NSPEC];  // 256 threads = 4 waves
    int chunk = blockIdx.x;
    int i = chunk * blockDim.x + threadIdx.x;
    int s = (i < n) ? cs[i] : -1;
    int lane = threadIdx.x & 63;
    int wave = threadIdx.x >> 6;

    int lanePrefix = 0;
    for (int sp = 0; sp < NSPEC; ++sp) {
        unsigned long long b = __ballot(s == sp);
        if (lane == 0) waveCnt[wave][sp] = __popcll(b);
        if (sp == s) lanePrefix = __popcll(b & ((1ull << lane) - 1ull));
    }
    __syncthreads();
    if (i < n) {
        int wp = 0;
        for (int w = 0; w < wave; ++w) wp += waveCnt[w][s];
        dest[i] = chunkOffsets[chunk * NSPEC + s] + wp + lanePrefix;
    }
}

// ---------- main per-pair scatter kernel ----------

__global__ void pair_kernel(const float* __restrict__ dirs,
                            const int* __restrict__ pci,
                            const int* __restrict__ nsi,
                            const int* __restrict__ dest,
                            float* __restrict__ out, int P) {
    int i = blockIdx.x * blockDim.x + threadIdx.x;
    if (i >= P) return;
    float x = dirs[3 * i + 0];
    float y = dirs[3 * i + 1];
    float z = dirs[3 * i + 2];
    float r2 = x * x + y * y + z * z;
    float r = sqrtf(r2);
    if (r >= RCUT) return;  // fc == 0 -> all contributions zero

    float fc = 0.5f * (cosf(3.14159265358979323846f * r * (1.0f / RCUT)) + 1.0f);
    float q = expf(-r2 * (1.0f / (RCUT * RCUT)));  // exp(-r^2/25); q^(n+1) = exp(-alpha_n r^2)

    int row = dest[pci[i]] * NFEAT;
    int s = nsi[i];
    float* o = out + row + s;

    float rl = fc;  // r^l * fc, starting l=0
    #pragma unroll
    for (int l = 0; l < 4; ++l) {
        float e = q;
        int nm = kNmax[l];
        int off = kOff[l];
        for (int n = 0; n < nm; ++n) {
            atomicAdd(o + off + n * NSPEC, rl * e);
            e *= q;
        }
        rl *= r;
    }
}

extern "C" void kernel_launch(void* const* d_in, const int* in_sizes, int n_in,
                              void* d_out, int out_size, void* d_ws, size_t ws_size,
                              hipStream_t stream) {
    const float* dirs = (const float*)d_in[0];
    const int* pci = (const int*)d_in[1];
    const int* nsi = (const int*)d_in[2];
    const int* cs = (const int*)d_in[3];
    int P = in_sizes[1];
    int NC = in_sizes[3];
    float* out = (float*)d_out;

    int nChunks = (NC + 255) / 256;
    int* chunkCounts  = (int*)d_ws;                    // nChunks*4
    int* chunkOffsets = chunkCounts + nChunks * NSPEC; // nChunks*4
    int* speciesBase  = chunkOffsets + nChunks * NSPEC;// 4
    int* dest         = speciesBase + NSPEC;           // NC

    zero_kernel<<<2048, 256, 0, stream>>>(out, out_size);
    count_kernel<<<nChunks, 256, 0, stream>>>(cs, NC, chunkCounts);
    scan_kernel<<<1, 256, 0, stream>>>(chunkCounts, nChunks, chunkOffsets, speciesBase);
    dest_kernel<<<nChunks, 256, 0, stream>>>(cs, NC, chunkOffsets, dest);
    pair_kernel<<<(P + 255) / 256, 256, 0, stream>>>(dirs, pci, nsi, dest, out, P);
}

// Round 3
// 365.565 us; speedup vs baseline: 9.0202x; 9.0202x over previous
//
#include <hip/hip_runtime.h>
#include <hip/hip_bf16.h>

#define NSPEC 4
#define NFEAT 144
#define RCUT 5.0f

// feature block offsets for l = 0..3 (n_max = 12,10,8,6; each block n_max*4 wide)
__device__ __constant__ int kNmax[4] = {12, 10, 8, 6};
__device__ __constant__ int kOff[4]  = {0, 48, 88, 120};

// ---------- utility ----------

__global__ void zero_i32(int* __restrict__ p, int n) {
    int i = blockIdx.x * blockDim.x + threadIdx.x;
    if (i < n) p[i] = 0;
}

__global__ void zero_f32(float* __restrict__ out, int n) {
    int n4 = n >> 2;
    float4* o4 = (float4*)out;
    for (int i = blockIdx.x * blockDim.x + threadIdx.x; i < n4; i += gridDim.x * blockDim.x) {
        o4[i] = make_float4(0.f, 0.f, 0.f, 0.f);
    }
    int tail = n & 3;
    if (blockIdx.x == 0 && threadIdx.x < tail) out[n4 * 4 + threadIdx.x] = 0.f;
}

// ---------- stable counting-sort rank of centers by species ----------

__global__ void count_kernel(const int* __restrict__ cs, int n, int* __restrict__ chunkCounts) {
    __shared__ int cnt[NSPEC];
    if (threadIdx.x < NSPEC) cnt[threadIdx.x] = 0;
    __syncthreads();
    int i = blockIdx.x * blockDim.x + threadIdx.x;
    if (i < n) atomicAdd(&cnt[cs[i]], 1);
    __syncthreads();
    if (threadIdx.x < NSPEC) chunkCounts[blockIdx.x * NSPEC + threadIdx.x] = cnt[threadIdx.x];
}

__global__ void scan_kernel(const int* __restrict__ chunkCounts, int nChunks,
                            int* __restrict__ chunkOffsets, int* __restrict__ speciesBase) {
    if (threadIdx.x < NSPEC) {
        int s = threadIdx.x;
        int run = 0;
        for (int c = 0; c < nChunks; ++c) {
            chunkOffsets[c * NSPEC + s] = run;
            run += chunkCounts[c * NSPEC + s];
        }
        speciesBase[s] = run;
    }
    __syncthreads();
    if (threadIdx.x == 0) {
        int base = 0;
        for (int s = 0; s < NSPEC; ++s) {
            int t = speciesBase[s];
            speciesBase[s] = base;
            base += t;
        }
    }
    __syncthreads();
    for (int i = threadIdx.x; i < nChunks * NSPEC; i += blockDim.x) {
        chunkOffsets[i] += speciesBase[i & (NSPEC - 1)];
    }
}

__global__ void dest_kernel(const int* __restrict__ cs, int n,
                            const int* __restrict__ chunkOffsets, int* __restrict__ dest) {
    __shared__ int waveCnt[4][NSPEC];
    int chunk = blockIdx.x;
    int i = chunk * blockDim.x + threadIdx.x;
    int s = (i < n) ? cs[i] : -1;
    int lane = threadIdx.x & 63;
    int wave = threadIdx.x >> 6;

    int lanePrefix = 0;
    for (int sp = 0; sp < NSPEC; ++sp) {
        unsigned long long b = __ballot(s == sp);
        if (lane == 0) waveCnt[wave][sp] = __popcll(b);
        if (sp == s) lanePrefix = __popcll(b & ((1ull << lane) - 1ull));
    }
    __syncthreads();
    if (i < n) {
        int wp = 0;
        for (int w = 0; w < wave; ++w) wp += waveCnt[w][s];
        dest[i] = chunkOffsets[chunk * NSPEC + s] + wp + lanePrefix;
    }
}

// ---------- pair binning: histogram over destination rows ----------

__global__ void hist_kernel(const float* __restrict__ dirs, const int* __restrict__ pci,
                            const int* __restrict__ dest, int* __restrict__ hist, int P) {
    int i = blockIdx.x * blockDim.x + threadIdx.x;
    if (i >= P) return;
    float x = dirs[3 * i + 0], y = dirs[3 * i + 1], z = dirs[3 * i + 2];
    float r2 = x * x + y * y + z * z;
    if (r2 >= RCUT * RCUT) return;
    atomicAdd(&hist[dest[pci[i]]], 1);
}

// ---------- hierarchical exclusive scan over NC bins (1024 elems / block) ----------

__global__ void scanA(const int* __restrict__ hist, int n, int* __restrict__ blockTot) {
    __shared__ int sdata[256];
    int base = blockIdx.x * 1024;
    int t = threadIdx.x;
    int i0 = base + t * 4;
    int v0 = (i0 + 0 < n) ? hist[i0 + 0] : 0;
    int v1 = (i0 + 1 < n) ? hist[i0 + 1] : 0;
    int v2 = (i0 + 2 < n) ? hist[i0 + 2] : 0;
    int v3 = (i0 + 3 < n) ? hist[i0 + 3] : 0;
    sdata[t] = v0 + v1 + v2 + v3;
    __syncthreads();
    for (int off = 1; off < 256; off <<= 1) {
        int x = (t >= off) ? sdata[t - off] : 0;
        __syncthreads();
        sdata[t] += x;
        __syncthreads();
    }
    if (t == 255) blockTot[blockIdx.x] = sdata[255];
}

__global__ void scanB(int* __restrict__ blockTot, int nb) {
    if (threadIdx.x == 0) {
        int run = 0;
        for (int b = 0; b < nb; ++b) {
            int t = blockTot[b];
            blockTot[b] = run;
            run += t;
        }
    }
}

__global__ void scanC(int* __restrict__ hist, int n, const int* __restrict__ blockBase) {
    __shared__ int sdata[256];
    int base = blockIdx.x * 1024;
    int t = threadIdx.x;
    int i0 = base + t * 4;
    int v0 = (i0 + 0 < n) ? hist[i0 + 0] : 0;
    int v1 = (i0 + 1 < n) ? hist[i0 + 1] : 0;
    int v2 = (i0 + 2 < n) ? hist[i0 + 2] : 0;
    int v3 = (i0 + 3 < n) ? hist[i0 + 3] : 0;
    sdata[t] = v0 + v1 + v2 + v3;
    __syncthreads();
    for (int off = 1; off < 256; off <<= 1) {
        int x = (t >= off) ? sdata[t - off] : 0;
        __syncthreads();
        sdata[t] += x;
        __syncthreads();
    }
    int ebase = blockBase[blockIdx.x] + ((t > 0) ? sdata[t - 1] : 0);
    if (i0 + 0 < n) hist[i0 + 0] = ebase;
    if (i0 + 1 < n) hist[i0 + 1] = ebase + v0;
    if (i0 + 2 < n) hist[i0 + 2] = ebase + v0 + v1;
    if (i0 + 3 < n) hist[i0 + 3] = ebase + v0 + v1 + v2;
}

// ---------- scatter pairs into sorted order (payload: r packed with species) ----------

__global__ void scatter_kernel(const float* __restrict__ dirs, const int* __restrict__ pci,
                               const int* __restrict__ nsi, const int* __restrict__ dest,
                               int* __restrict__ offsets, unsigned* __restrict__ sorted, int P) {
    int i = blockIdx.x * blockDim.x + threadIdx.x;
    if (i >= P) return;
    float x = dirs[3 * i + 0], y = dirs[3 * i + 1], z = dirs[3 * i + 2];
    float r2 = x * x + y * y + z * z;
    if (r2 >= RCUT * RCUT) return;
    float r = sqrtf(r2);
    int key = dest[pci[i]];
    int pos = atomicAdd(&offsets[key], 1);
    unsigned u = (__float_as_uint(r) & ~3u) | (unsigned)nsi[i];
    sorted[pos] = u;
}

// ---------- accumulate: one wave per output row, lanes own output columns ----------

__global__ void accum_kernel(const int* __restrict__ offs /* post-scatter: offs[k]=end of bin k */,
                             const unsigned* __restrict__ sorted,
                             float* __restrict__ out, int NC) {
    int gid = blockIdx.x * blockDim.x + threadIdx.x;
    int w = gid >> 6;
    int lane = gid & 63;
    if (w >= NC) return;

    int start = (w == 0) ? 0 : offs[w - 1];
    int end = offs[w];

    // decode per-lane constants for output columns o = lane, lane+64, lane+128
    int l0, n0, l1, n1, l2, n2;
    {
        int o = lane;
        if (o < 48)       { l0 = 0; n0 = o >> 2; }
        else if (o < 88)  { l0 = 1; n0 = (o - 48) >> 2; }
        else              { l0 = 2; n0 = (o - 88) >> 2; }  // lane<64 so o<112 here
        o = lane + 64;
        if (o < 88)       { l1 = 1; n1 = (o - 48) >> 2; }
        else if (o < 120) { l1 = 2; n1 = (o - 88) >> 2; }
        else              { l1 = 3; n1 = (o - 120) >> 2; }
        o = lane + 128;
        l2 = 3; n2 = (o - 120) >> 2;  // only lanes 0..15 valid (o<144)
    }
    int s0 = lane & 3, s1 = s0, s2 = s0;
    float c0 = -(float)(n0 + 1) / (RCUT * RCUT);
    float c1 = -(float)(n1 + 1) / (RCUT * RCUT);
    float c2 = -(float)(n2 + 1) / (RCUT * RCUT);

    float acc0 = 0.f, acc1 = 0.f, acc2 = 0.f;
    for (int p = start; p < end; ++p) {
        unsigned u = sorted[p];
        int sp = (int)(u & 3u);
        float r = __uint_as_float(u & ~3u);
        float r2 = r * r;
        float r3 = r2 * r;
        float fc = 0.5f * (__cosf(3.14159265358979323846f * r * (1.0f / RCUT)) + 1.0f);
        float rl0 = (l0 == 0) ? 1.f : ((l0 == 1) ? r : r2);
        float rl1 = (l1 == 1) ? r : ((l1 == 2) ? r2 : r3);
        float rl2 = r3;
        acc0 += (sp == s0) ? fc * rl0 * __expf(c0 * r2) : 0.f;
        acc1 += (sp == s1) ? fc * rl1 * __expf(c1 * r2) : 0.f;
        acc2 += (sp == s2) ? fc * rl2 * __expf(c2 * r2) : 0.f;
    }

    float* orow = out + (size_t)w * NFEAT;
    orow[lane] = acc0;
    orow[lane + 64] = acc1;
    if (lane + 128 < NFEAT) orow[lane + 128] = acc2;
}

// ---------- fallback: direct atomic scatter (round-2 path) ----------

__global__ void pair_kernel(const float* __restrict__ dirs,
                            const int* __restrict__ pci,
                            const int* __restrict__ nsi,
                            const int* __restrict__ dest,
                            float* __restrict__ out, int P) {
    int i = blockIdx.x * blockDim.x + threadIdx.x;
    if (i >= P) return;
    float x = dirs[3 * i + 0], y = dirs[3 * i + 1], z = dirs[3 * i + 2];
    float r2 = x * x + y * y + z * z;
    float r = sqrtf(r2);
    if (r >= RCUT) return;
    float fc = 0.5f * (cosf(3.14159265358979323846f * r * (1.0f / RCUT)) + 1.0f);
    float q = expf(-r2 * (1.0f / (RCUT * RCUT)));
    int row = dest[pci[i]] * NFEAT;
    int s = nsi[i];
    float* o = out + row + s;
    float rl = fc;
    #pragma unroll
    for (int l = 0; l < 4; ++l) {
        float e = q;
        int nm = kNmax[l];
        int off = kOff[l];
        for (int n = 0; n < nm; ++n) {
            atomicAdd(o + off + n * NSPEC, rl * e);
            e *= q;
        }
        rl *= r;
    }
}

extern "C" void kernel_launch(void* const* d_in, const int* in_sizes, int n_in,
                              void* d_out, int out_size, void* d_ws, size_t ws_size,
                              hipStream_t stream) {
    const float* dirs = (const float*)d_in[0];
    const int* pci = (const int*)d_in[1];
    const int* nsi = (const int*)d_in[2];
    const int* cs = (const int*)d_in[3];
    int P = in_sizes[1];
    int NC = in_sizes[3];
    float* out = (float*)d_out;

    int nChunks = (NC + 255) / 256;
    int NB = (NC + 1023) / 1024;

    // ws layout (ints)
    int* chunkCounts  = (int*)d_ws;                      // nChunks*4
    int* chunkOffsets = chunkCounts + nChunks * NSPEC;   // nChunks*4
    int* speciesBase  = chunkOffsets + nChunks * NSPEC;  // 4
    int* dest         = speciesBase + NSPEC;             // NC
    int* hist         = dest + NC;                       // NC (becomes offsets)
    int* blockTot     = hist + NC;                       // NB
    unsigned* sorted  = (unsigned*)(blockTot + NB);      // P

    size_t need = ((size_t)(2 * nChunks * NSPEC + NSPEC) + 2 * (size_t)NC + NB + (size_t)P) * sizeof(int);

    // center -> sorted-row map (always needed)
    count_kernel<<<nChunks, 256, 0, stream>>>(cs, NC, chunkCounts);
    scan_kernel<<<1, 256, 0, stream>>>(chunkCounts, nChunks, chunkOffsets, speciesBase);
    dest_kernel<<<nChunks, 256, 0, stream>>>(cs, NC, chunkOffsets, dest);

    if (ws_size >= need) {
        // sorted-binning path, no output atomics
        zero_i32<<<(NC + 255) / 256, 256, 0, stream>>>(hist, NC);
        hist_kernel<<<(P + 255) / 256, 256, 0, stream>>>(dirs, pci, dest, hist, P);
        scanA<<<NB, 256, 0, stream>>>(hist, NC, blockTot);
        scanB<<<1, 64, 0, stream>>>(blockTot, NB);
        scanC<<<NB, 256, 0, stream>>>(hist, NC, blockTot);
        scatter_kernel<<<(P + 255) / 256, 256, 0, stream>>>(dirs, pci, nsi, dest, hist, sorted, P);
        accum_kernel<<<(NC + 3) / 4, 256, 0, stream>>>(hist, sorted, out, NC);
    } else {
        // fallback: direct atomics
        zero_f32<<<2048, 256, 0, stream>>>(out, out_size);
        pair_kernel<<<(P + 255) / 256, 256, 0, stream>>>(dirs, pci, nsi, dest, out, P);
    }
}